// Round 1
// baseline (94.053 us; speedup 1.0000x reference)
//
#include <hip/hip_runtime.h>

// reblurWithKernel: out[c,h,w] = sum_{i,j in 0..2} img[c, clamp(h+i-1), clamp(w+j-1)] * K[i*3+j, h, w]
// img: [3,1024,1024] f32, K: [9,1024,1024] f32, out: [3,1024,1024] f32.
// Memory-bound (~60 MB traffic). One thread = 4 consecutive pixels (float4).

#define H 1024
#define W 1024

__global__ __launch_bounds__(256) void reblur_kernel(
    const float* __restrict__ img,   // [3, H, W]
    const float* __restrict__ ker,   // [9, H, W]
    float* __restrict__ out)         // [3, H, W]
{
    const int tid = blockIdx.x * blockDim.x + threadIdx.x;   // 0 .. H*W/4-1
    const int w4  = tid & (W / 4 - 1);                       // float4 index in row
    const int h   = tid >> 8;                                // W/4 == 256
    const int w0  = w4 * 4;

    // ---- load the 9 per-pixel kernel taps (coalesced float4) ----
    float4 kv[9];
    const float* kbase = ker + (size_t)h * W + w0;
    #pragma unroll
    for (int t = 0; t < 9; ++t)
        kv[t] = *reinterpret_cast<const float4*>(kbase + (size_t)t * H * W);

    // clamped neighbor rows (edge replication)
    const int hm = (h == 0)     ? 0     : h - 1;
    const int hp = (h == H - 1) ? H - 1 : h + 1;
    const int rows[3] = { hm, h, hp };

    float4 acc[3];
    #pragma unroll
    for (int c = 0; c < 3; ++c) {
        float s0 = 0.f, s1 = 0.f, s2 = 0.f, s3 = 0.f;
        const float* cimg = img + (size_t)c * H * W;
        #pragma unroll
        for (int r = 0; r < 3; ++r) {
            const float* rp = cimg + (size_t)rows[r] * W + w0;
            const float4 ctr = *reinterpret_cast<const float4*>(rp);
            const float left  = (w0 == 0)     ? ctr.x : rp[-1];  // clamp w-1
            const float right = (w0 == W - 4) ? ctr.w : rp[4];   // clamp w+1 at 1023
            const float v0 = left, v1 = ctr.x, v2 = ctr.y,
                        v3 = ctr.z, v4 = ctr.w, v5 = right;
            // j = 0: dx = -1 ; j = 1: dx = 0 ; j = 2: dx = +1
            {
                const float4 k = kv[r * 3 + 0];
                s0 = fmaf(v0, k.x, s0); s1 = fmaf(v1, k.y, s1);
                s2 = fmaf(v2, k.z, s2); s3 = fmaf(v3, k.w, s3);
            }
            {
                const float4 k = kv[r * 3 + 1];
                s0 = fmaf(v1, k.x, s0); s1 = fmaf(v2, k.y, s1);
                s2 = fmaf(v3, k.z, s2); s3 = fmaf(v4, k.w, s3);
            }
            {
                const float4 k = kv[r * 3 + 2];
                s0 = fmaf(v2, k.x, s0); s1 = fmaf(v3, k.y, s1);
                s2 = fmaf(v4, k.z, s2); s3 = fmaf(v5, k.w, s3);
            }
        }
        acc[c] = make_float4(s0, s1, s2, s3);
    }

    #pragma unroll
    for (int c = 0; c < 3; ++c)
        *reinterpret_cast<float4*>(out + (size_t)c * H * W + (size_t)h * W + w0) = acc[c];
}

extern "C" void kernel_launch(void* const* d_in, const int* in_sizes, int n_in,
                              void* d_out, int out_size, void* d_ws, size_t ws_size,
                              hipStream_t stream) {
    const float* img = (const float*)d_in[0];   // [1,3,1024,1024]
    const float* ker = (const float*)d_in[1];   // [9,1024,1024]
    float* out = (float*)d_out;                 // [1,3,1024,1024]

    const int threads = (H * W) / 4;            // 262144
    const int block = 256;
    const int grid = threads / block;           // 1024
    reblur_kernel<<<grid, block, 0, stream>>>(img, ker, out);
}